// Round 4
// baseline (90.651 us; speedup 1.0000x reference)
//
#include <hip/hip_runtime.h>

#define HEADS 8
#define NTOK 4096
#define CH 128
#define KSPLIT 8
#define KCHUNK (NTOK / KSPLIT)   // 512
#define QTILE 128
#define NQT (NTOK / QTILE)       // 32
#define LN_EPS 1e-5f

typedef short short8 __attribute__((ext_vector_type(8)));
typedef float f32x4 __attribute__((ext_vector_type(4)));
typedef float f32x2 __attribute__((ext_vector_type(2)));
typedef float f32x16 __attribute__((ext_vector_type(16)));

__device__ inline unsigned short f2bf(float f) {
    unsigned int u = __float_as_uint(f);
    u = (u + 0x7FFFu + ((u >> 16) & 1u)) >> 16;
    return (unsigned short)u;
}

__device__ inline float fast_exp2(float x) {
#if __has_builtin(__builtin_amdgcn_exp2f)
    return __builtin_amdgcn_exp2f(x);
#else
    float r; asm volatile("v_exp_f32 %0, %1" : "=v"(r) : "v"(x)); return r;
#endif
}

// packed f32 fma: lowers to v_pk_fma_f32 (VOP3P)
__device__ inline f32x2 fma2(f32x2 a, f32x2 b, f32x2 c) {
#if __has_builtin(__builtin_elementwise_fma)
    return __builtin_elementwise_fma(a, b, c);
#else
    f32x2 r; r.x = fmaf(a.x, b.x, c.x); r.y = fmaf(a.y, b.y, c.y); return r;
#endif
}

// softmax scale * log2(e), folded into q columns of W
#define SC (0.08838834764831845f * 1.4426950408889634f)

// ---------------------------------------------------------------------------
// Kernel A: LayerNorm + QK projection via MFMA, W-fragments built inline.
// Block = 16 rows x 4 waves; blockIdx.y = ct-group of 4; wave w owns
// ct = ctg*4 + w (ct<8 -> q head ct, ct>=8 -> k head ct-8).
// LDS tile is XOR-swizzled (c ^= (row&7)<<3 in shorts) to break the 16-way
// bank conflict on the ds_read_b128 A-fragment reads (row stride = 256 B).
// blockIdx.y==0 blocks additionally transpose A -> vT[h][n]; block (0,0)
// zeroes the split-K arrival counters for kernel B (stream order guarantees
// visibility; workspace is re-poisoned between harness iterations).
// ---------------------------------------------------------------------------
__global__ __launch_bounds__(256) void ln_qk_fused(
    const float* __restrict__ x, const float* __restrict__ Wqk,
    const float* __restrict__ g, const float* __restrict__ b,
    const float* __restrict__ A,
    unsigned short* __restrict__ qb, unsigned short* __restrict__ kbuf,
    float* __restrict__ vT, unsigned int* __restrict__ cnt)
{
    __shared__ __align__(16) unsigned short xn_s[16][CH];   // bf16, 4 KB
    const int tid = threadIdx.x;
    const int wave = tid >> 6, lane = tid & 63;
    const int row0 = blockIdx.x * 16;
    const int ct = blockIdx.y * 4 + wave;
    const int j = lane & 15, grp = lane >> 4;

    if (blockIdx.x == 0 && blockIdx.y == 0)
        cnt[tid] = 0;                          // 256 counters, 256 threads

    // Build B-fragments for this ct directly from W (L2-resident, 128 KB).
    // wf[ks]: lane holds W[ks*32 + grp*8 + jj][ct*16 + j], jj = 0..7.
    const float sc = (ct < 8) ? SC : 1.0f;
    short8 wf[4];
    #pragma unroll
    for (int ks = 0; ks < 4; ++ks) {
        unsigned int uu0, uu1, uu2, uu3;
        const float* wp = Wqk + (ks * 32 + grp * 8) * 256 + ct * 16 + j;
        uu0 = f2bf(wp[0 * 256] * sc) | ((unsigned)f2bf(wp[1 * 256] * sc) << 16);
        uu1 = f2bf(wp[2 * 256] * sc) | ((unsigned)f2bf(wp[3 * 256] * sc) << 16);
        uu2 = f2bf(wp[4 * 256] * sc) | ((unsigned)f2bf(wp[5 * 256] * sc) << 16);
        uu3 = f2bf(wp[6 * 256] * sc) | ((unsigned)f2bf(wp[7 * 256] * sc) << 16);
        uint4 packed = {uu0, uu1, uu2, uu3};
        wf[ks] = *(short8*)&packed;
    }

    // A transpose side-task (one ct-group is enough): vT[h][n] = A[n][h]
    if (blockIdx.y == 0 && tid < 128) {
        const int hh = tid >> 4, r = tid & 15;
        vT[hh * NTOK + row0 + r] = A[(size_t)(row0 + r) * HEADS + hh];
    }

    // LayerNorm: each wave handles 4 rows, 2 elements/lane
    for (int rr = wave; rr < 16; rr += 4) {
        const int row = row0 + rr;
        float2 xv = *(const float2*)(x + row * CH + lane * 2);
        float s  = xv.x + xv.y;
        float sq = xv.x * xv.x + xv.y * xv.y;
        #pragma unroll
        for (int off = 32; off >= 1; off >>= 1) {
            s  += __shfl_xor(s, off);
            sq += __shfl_xor(sq, off);
        }
        float mu  = s * (1.0f / CH);
        float var = sq * (1.0f / CH) - mu * mu;
        float rs  = rsqrtf(var + LN_EPS);
        float2 gv = *(const float2*)(g + lane * 2);
        float2 bv = *(const float2*)(b + lane * 2);
        unsigned int lo = f2bf((xv.x - mu) * rs * gv.x + bv.x);
        unsigned int hi = f2bf((xv.y - mu) * rs * gv.y + bv.y);
        const int c = (lane * 2) ^ ((rr & 7) << 3);      // swizzled column
        *(unsigned int*)&xn_s[rr][c] = lo | (hi << 16);
    }
    __syncthreads();

    // A-fragments: lane holds xn[row = lane&15][ks*32 + grp*8 + jj] (deswizzled)
    short8 af[4];
    #pragma unroll
    for (int ks = 0; ks < 4; ++ks)
        af[ks] = *(const short8*)(&xn_s[j][(ks * 32 + grp * 8) ^ ((j & 7) << 3)]);

    f32x4 acc = {0.f, 0.f, 0.f, 0.f};
    #pragma unroll
    for (int ks = 0; ks < 4; ++ks)
        acc = __builtin_amdgcn_mfma_f32_16x16x32_bf16(af[ks], wf[ks], acc, 0, 0, 0);

    // C/D layout: row = grp*4 + r, col = j
    unsigned short* dst = (ct < 8)
        ? qb   + ((size_t)ct * NTOK + row0) * 16
        : kbuf + ((size_t)(ct - 8) * NTOK + row0) * 16;
    #pragma unroll
    for (int r = 0; r < 4; ++r)
        dst[(grp * 4 + r) * 16 + j] = f2bf(acc[r]);
}

// ---------------------------------------------------------------------------
// Kernel B: MFMA attention partials via 32x32x16 (K = hd = 16, exact),
// with fused split-K reduction (last-arrival block finishes the output).
// One MFMA per 32 keys x 32 queries: K tile is the A-operand
// (lane holds K[m + (lane&31)][k = (lane>>5)*8 + jj]), Q the B-operand
// (lane holds Q[q0 + (lane&31)][k = (lane>>5)*8 + jj]).
// C/D map: reg r -> key (r&3) + 8*(r>>2) + 4*(lane>>5), col -> query lane&31.
// Each lane owns ONE query column: E/F are scalars; final reduce is a single
// shfl_xor(32). v broadcast from pre-transposed vT as 4 float4 per iter.
// Partials layout [(qt,h)][s][128]: coalesced on both store and reduce-read.
// ---------------------------------------------------------------------------
__global__ __launch_bounds__(256) void attn_kernel(
    const unsigned short* __restrict__ qb, const unsigned short* __restrict__ kbuf,
    const float* __restrict__ vT, const float* __restrict__ A,
    const float* __restrict__ Wv,
    float* __restrict__ partE, float* __restrict__ partF,
    unsigned int* __restrict__ cnt, float* __restrict__ out)
{
    const int tid = threadIdx.x;
    const int wave = tid >> 6, lane = tid & 63;
    const int qt = blockIdx.x, ksp = blockIdx.y, h = blockIdx.z;
    const int q0 = qt * QTILE + wave * 32;
    const int m0 = ksp * KCHUNK;
    const int c  = lane & 31;      // row (key) / col (query) within tile
    const int hi = lane >> 5;      // k-dim half (0: k=0..7, 1: k=8..15)

    // Q as B-operand: lane holds Q[q0 + c][hi*8 + jj]
    short8 qf = *(const short8*)(qb + ((size_t)(h * NTOK + q0 + c) * 16 + hi * 8));

    // K as A-operand: lane holds K[m + c][hi*8 + jj]
    const unsigned short* kl = kbuf + ((size_t)(h * NTOK + m0 + c) * 16 + hi * 8);
    // v for reg-group g: keys m + 8g + 4*hi + {0..3}
    const float* vl = vT + h * NTOK + m0 + hi * 4;

    f32x2 E2 = {0.f, 0.f}, F2 = {0.f, 0.f};
    short8 kf = *(const short8*)kl;

    for (int mi = 0; mi < KCHUNK; mi += 32) {
        const int nx = (mi + 32 < KCHUNK) ? mi + 32 : 0;   // wrap: dead prefetch
        short8 kn = *(const short8*)(kl + (size_t)nx * 16);

        f32x4 v0 = *(const f32x4*)(vl + mi);
        f32x4 v1 = *(const f32x4*)(vl + mi + 8);
        f32x4 v2 = *(const f32x4*)(vl + mi + 16);
        f32x4 v3 = *(const f32x4*)(vl + mi + 24);

        f32x16 z = {0.f};
        f32x16 s = __builtin_amdgcn_mfma_f32_32x32x16_bf16(kf, qf, z, 0, 0, 0);

        #pragma unroll
        for (int gg = 0; gg < 4; ++gg) {
            f32x4 vg = (gg == 0) ? v0 : (gg == 1) ? v1 : (gg == 2) ? v2 : v3;
            f32x2 pa, pb;
            pa.x = fast_exp2(s[gg * 4 + 0]);
            pa.y = fast_exp2(s[gg * 4 + 1]);
            pb.x = fast_exp2(s[gg * 4 + 2]);
            pb.y = fast_exp2(s[gg * 4 + 3]);
            E2 += pa;
            E2 += pb;
            F2 = fma2(pa, vg.xy, F2);
            F2 = fma2(pb, vg.zw, F2);
        }
        kf = kn;
    }

    float e = E2.x + E2.y;
    float f = F2.x + F2.y;
    e += __shfl_xor(e, 32);
    f += __shfl_xor(f, 32);

    // partials: [(qt,h)][s][128] — 32 consecutive floats per wave
    const int slot = (qt * HEADS + h) * KSPLIT + ksp;
    if (lane < 32) {
        partE[slot * QTILE + wave * 32 + c] = e;
        partF[slot * QTILE + wave * 32 + c] = f;
    }

    // --- last-arrival block reduces this (qt,h) tile ---
    __shared__ bool last_s;
    __syncthreads();
    if (tid == 0) {
        __threadfence();                               // release partials
        unsigned int old = atomicAdd(&cnt[qt * HEADS + h], 1u);
        last_s = (old == KSPLIT - 1);
    }
    __syncthreads();
    if (!last_s) return;
    __threadfence();                                   // acquire others' partials

    if (tid < QTILE) {
        const int q = qt * QTILE + tid;
        const float* pe = partE + (size_t)(qt * HEADS + h) * KSPLIT * QTILE + tid;
        const float* pf = partF + (size_t)(qt * HEADS + h) * KSPLIT * QTILE + tid;
        float E = 0.f, F = 0.f;
        #pragma unroll
        for (int s = 0; s < KSPLIT; ++s) {
            E += pe[s * QTILE];
            F += pf[s * QTILE];
        }
        out[q * HEADS + h] = A[q * HEADS + h] + Wv[0] * F / E;
    }
}

// ---------------------------------------------------------------------------
extern "C" void kernel_launch(void* const* d_in, const int* in_sizes, int n_in,
                              void* d_out, int out_size, void* d_ws, size_t ws_size,
                              hipStream_t stream)
{
    const float* x   = (const float*)d_in[0];
    const float* A   = (const float*)d_in[1];
    const float* Wqk = (const float*)d_in[2];
    const float* Wv  = (const float*)d_in[3];
    const float* g   = (const float*)d_in[4];
    const float* b   = (const float*)d_in[5];
    float* out = (float*)d_out;

    float* partE = (float*)d_ws;                                  // 1 MB
    float* partF = partE + (size_t)NQT * HEADS * KSPLIT * QTILE;  // 1 MB
    unsigned short* qb   = (unsigned short*)(partF + (size_t)NQT * HEADS * KSPLIT * QTILE); // 1 MB
    unsigned short* kbuf = qb + (size_t)HEADS * NTOK * 16;        // 1 MB
    float* vT = (float*)(kbuf + (size_t)HEADS * NTOK * 16);       // 128 KB
    unsigned int* cnt = (unsigned int*)(vT + (size_t)HEADS * NTOK); // 1 KB

    ln_qk_fused<<<dim3(NTOK / 16, 4), dim3(256), 0, stream>>>(
        x, Wqk, g, b, A, qb, kbuf, vT, cnt);
    attn_kernel<<<dim3(NQT, KSPLIT, HEADS), dim3(256), 0, stream>>>(
        qb, kbuf, vT, A, Wv, partE, partF, cnt, out);
}

// Round 5
// 34.676 us; speedup vs baseline: 2.6143x; 2.6143x over previous
//
#include <hip/hip_runtime.h>

#define HEADS 8
#define NTOK 4096
#define CH 128
#define KSPLIT 4
#define KCHUNK (NTOK / KSPLIT)   // 1024
#define QTILE 128
#define NQT (NTOK / QTILE)       // 32
#define LN_EPS 1e-5f

typedef short short8 __attribute__((ext_vector_type(8)));
typedef float f32x4 __attribute__((ext_vector_type(4)));
typedef float f32x2 __attribute__((ext_vector_type(2)));
typedef float f32x16 __attribute__((ext_vector_type(16)));

__device__ inline unsigned short f2bf(float f) {
    unsigned int u = __float_as_uint(f);
    u = (u + 0x7FFFu + ((u >> 16) & 1u)) >> 16;
    return (unsigned short)u;
}

__device__ inline float fast_exp2(float x) {
#if __has_builtin(__builtin_amdgcn_exp2f)
    return __builtin_amdgcn_exp2f(x);
#else
    float r; asm volatile("v_exp_f32 %0, %1" : "=v"(r) : "v"(x)); return r;
#endif
}

// packed f32 fma: lowers to v_pk_fma_f32 (VOP3P)
__device__ inline f32x2 fma2(f32x2 a, f32x2 b, f32x2 c) {
#if __has_builtin(__builtin_elementwise_fma)
    return __builtin_elementwise_fma(a, b, c);
#else
    f32x2 r; r.x = fmaf(a.x, b.x, c.x); r.y = fmaf(a.y, b.y, c.y); return r;
#endif
}

// softmax scale * log2(e), folded into q columns of W
#define SC (0.08838834764831845f * 1.4426950408889634f)

// ---------------------------------------------------------------------------
// Kernel A: LayerNorm + QK projection via MFMA, W-fragments built inline.
// Block = 16 rows x 4 waves; blockIdx.y = ct-group of 4; wave w owns
// ct = ctg*4 + w (ct<8 -> q head ct, ct>=8 -> k head ct-8).
// LDS tile is XOR-swizzled (c ^= (row&7)<<3 in shorts) to break the 16-way
// bank conflict on the ds_read_b128 A-fragment reads (row stride = 256 B).
// blockIdx.y==0 blocks additionally transpose A -> vT[h][n] for kernel B.
// ---------------------------------------------------------------------------
__global__ __launch_bounds__(256) void ln_qk_fused(
    const float* __restrict__ x, const float* __restrict__ Wqk,
    const float* __restrict__ g, const float* __restrict__ b,
    const float* __restrict__ A,
    unsigned short* __restrict__ qb, unsigned short* __restrict__ kbuf,
    float* __restrict__ vT)
{
    __shared__ __align__(16) unsigned short xn_s[16][CH];   // bf16, 4 KB
    const int tid = threadIdx.x;
    const int wave = tid >> 6, lane = tid & 63;
    const int row0 = blockIdx.x * 16;
    const int ct = blockIdx.y * 4 + wave;
    const int j = lane & 15, grp = lane >> 4;

    // Build B-fragments for this ct directly from W (L2-resident, 128 KB).
    // wf[ks]: lane holds W[ks*32 + grp*8 + jj][ct*16 + j], jj = 0..7.
    const float sc = (ct < 8) ? SC : 1.0f;
    short8 wf[4];
    #pragma unroll
    for (int ks = 0; ks < 4; ++ks) {
        unsigned int uu0, uu1, uu2, uu3;
        const float* wp = Wqk + (ks * 32 + grp * 8) * 256 + ct * 16 + j;
        uu0 = f2bf(wp[0 * 256] * sc) | ((unsigned)f2bf(wp[1 * 256] * sc) << 16);
        uu1 = f2bf(wp[2 * 256] * sc) | ((unsigned)f2bf(wp[3 * 256] * sc) << 16);
        uu2 = f2bf(wp[4 * 256] * sc) | ((unsigned)f2bf(wp[5 * 256] * sc) << 16);
        uu3 = f2bf(wp[6 * 256] * sc) | ((unsigned)f2bf(wp[7 * 256] * sc) << 16);
        uint4 packed = {uu0, uu1, uu2, uu3};
        wf[ks] = *(short8*)&packed;
    }

    // A transpose side-task (one ct-group is enough): vT[h][n] = A[n][h]
    if (blockIdx.y == 0 && tid < 128) {
        const int hh = tid >> 4, r = tid & 15;
        vT[hh * NTOK + row0 + r] = A[(size_t)(row0 + r) * HEADS + hh];
    }

    // LayerNorm: each wave handles 4 rows, 2 elements/lane
    for (int rr = wave; rr < 16; rr += 4) {
        const int row = row0 + rr;
        float2 xv = *(const float2*)(x + row * CH + lane * 2);
        float s  = xv.x + xv.y;
        float sq = xv.x * xv.x + xv.y * xv.y;
        #pragma unroll
        for (int off = 32; off >= 1; off >>= 1) {
            s  += __shfl_xor(s, off);
            sq += __shfl_xor(sq, off);
        }
        float mu  = s * (1.0f / CH);
        float var = sq * (1.0f / CH) - mu * mu;
        float rs  = rsqrtf(var + LN_EPS);
        float2 gv = *(const float2*)(g + lane * 2);
        float2 bv = *(const float2*)(b + lane * 2);
        unsigned int lo = f2bf((xv.x - mu) * rs * gv.x + bv.x);
        unsigned int hi = f2bf((xv.y - mu) * rs * gv.y + bv.y);
        const int c = (lane * 2) ^ ((rr & 7) << 3);      // swizzled column
        *(unsigned int*)&xn_s[rr][c] = lo | (hi << 16);
    }
    __syncthreads();

    // A-fragments: lane holds xn[row = lane&15][ks*32 + grp*8 + jj] (deswizzled)
    short8 af[4];
    #pragma unroll
    for (int ks = 0; ks < 4; ++ks)
        af[ks] = *(const short8*)(&xn_s[j][(ks * 32 + grp * 8) ^ ((j & 7) << 3)]);

    f32x4 acc = {0.f, 0.f, 0.f, 0.f};
    #pragma unroll
    for (int ks = 0; ks < 4; ++ks)
        acc = __builtin_amdgcn_mfma_f32_16x16x32_bf16(af[ks], wf[ks], acc, 0, 0, 0);

    // C/D layout: row = grp*4 + r, col = j
    unsigned short* dst = (ct < 8)
        ? qb   + ((size_t)ct * NTOK + row0) * 16
        : kbuf + ((size_t)(ct - 8) * NTOK + row0) * 16;
    #pragma unroll
    for (int r = 0; r < 4; ++r)
        dst[(grp * 4 + r) * 16 + j] = f2bf(acc[r]);
}

// ---------------------------------------------------------------------------
// Kernel B: MFMA attention partials via 32x32x16 (K = hd = 16, exact).
// One MFMA per 32 keys x 32 queries: K tile is the A-operand
// (lane holds K[m + (lane&31)][k = (lane>>5)*8 + jj]), Q the B-operand
// (lane holds Q[q0 + (lane&31)][k = (lane>>5)*8 + jj]).
// C/D map: reg r -> key (r&3) + 8*(r>>2) + 4*(lane>>5), col -> query lane&31.
// Each lane owns ONE query column: E/F are scalars; final reduce is a single
// shfl_xor(32). v broadcast from pre-transposed vT as 4 float4 per iter.
// Partials layout [(qt,h)][s][QTILE]: 128 B contiguous per wave store,
// perfectly coalesced reduce-side reads. NO device fences (r4 lesson:
// per-block __threadfence = L2 writeback/invalidate storm on 8 XCDs).
// ---------------------------------------------------------------------------
__global__ __launch_bounds__(256) void attn_kernel(
    const unsigned short* __restrict__ qb, const unsigned short* __restrict__ kbuf,
    const float* __restrict__ vT,
    float* __restrict__ partE, float* __restrict__ partF)
{
    const int tid = threadIdx.x;
    const int wave = tid >> 6, lane = tid & 63;
    const int qt = blockIdx.x, ksp = blockIdx.y, h = blockIdx.z;
    const int q0 = qt * QTILE + wave * 32;
    const int m0 = ksp * KCHUNK;
    const int c  = lane & 31;      // row (key) / col (query) within tile
    const int hi = lane >> 5;      // k-dim half (0: k=0..7, 1: k=8..15)

    // Q as B-operand: lane holds Q[q0 + c][hi*8 + jj]
    short8 qf = *(const short8*)(qb + ((size_t)(h * NTOK + q0 + c) * 16 + hi * 8));

    // K as A-operand: lane holds K[m + c][hi*8 + jj]
    const unsigned short* kl = kbuf + ((size_t)(h * NTOK + m0 + c) * 16 + hi * 8);
    // v for reg-group g: keys m + 8g + 4*hi + {0..3}
    const float* vl = vT + h * NTOK + m0 + hi * 4;

    f32x2 E2 = {0.f, 0.f}, F2 = {0.f, 0.f};
    short8 kf = *(const short8*)kl;

    for (int mi = 0; mi < KCHUNK; mi += 32) {
        const int nx = (mi + 32 < KCHUNK) ? mi + 32 : 0;   // wrap: dead prefetch
        short8 kn = *(const short8*)(kl + (size_t)nx * 16);

        f32x4 v0 = *(const f32x4*)(vl + mi);
        f32x4 v1 = *(const f32x4*)(vl + mi + 8);
        f32x4 v2 = *(const f32x4*)(vl + mi + 16);
        f32x4 v3 = *(const f32x4*)(vl + mi + 24);

        f32x16 z = {0.f};
        f32x16 s = __builtin_amdgcn_mfma_f32_32x32x16_bf16(kf, qf, z, 0, 0, 0);

        #pragma unroll
        for (int gg = 0; gg < 4; ++gg) {
            f32x4 vg = (gg == 0) ? v0 : (gg == 1) ? v1 : (gg == 2) ? v2 : v3;
            f32x2 pa, pb;
            pa.x = fast_exp2(s[gg * 4 + 0]);
            pa.y = fast_exp2(s[gg * 4 + 1]);
            pb.x = fast_exp2(s[gg * 4 + 2]);
            pb.y = fast_exp2(s[gg * 4 + 3]);
            E2 += pa;
            E2 += pb;
            F2 = fma2(pa, vg.xy, F2);
            F2 = fma2(pb, vg.zw, F2);
        }
        kf = kn;
    }

    float e = E2.x + E2.y;
    float f = F2.x + F2.y;
    e += __shfl_xor(e, 32);
    f += __shfl_xor(f, 32);

    // partials: [(qt,h)][s][QTILE] — 32 consecutive floats per wave
    if (lane < 32) {
        const size_t slot = ((size_t)(qt * HEADS + h) * KSPLIT + ksp) * QTILE;
        partE[slot + wave * 32 + c] = e;
        partF[slot + wave * 32 + c] = f;
    }
}

// ---------------------------------------------------------------------------
// Kernel C: reduce k-splits, out = A + wv * F / E
// Thread t -> pair = (qt,h) = t>>7, i = t&127: partial reads fully coalesced.
// ---------------------------------------------------------------------------
__global__ __launch_bounds__(256) void reduce_kernel(
    const float* __restrict__ partE, const float* __restrict__ partF,
    const float* __restrict__ A, const float* __restrict__ Wv,
    float* __restrict__ out)
{
    const int t = blockIdx.x * 256 + threadIdx.x;   // 0..32767
    const int pair = t >> 7;          // qt*HEADS + h
    const int i = t & (QTILE - 1);
    const int q = (pair >> 3) * QTILE + i;
    const int h = pair & 7;
    const float* pe = partE + (size_t)pair * KSPLIT * QTILE + i;
    const float* pf = partF + (size_t)pair * KSPLIT * QTILE + i;
    float E = 0.f, F = 0.f;
    #pragma unroll
    for (int s = 0; s < KSPLIT; ++s) {
        E += pe[s * QTILE];
        F += pf[s * QTILE];
    }
    out[q * HEADS + h] = A[q * HEADS + h] + Wv[0] * F / E;
}

// ---------------------------------------------------------------------------
extern "C" void kernel_launch(void* const* d_in, const int* in_sizes, int n_in,
                              void* d_out, int out_size, void* d_ws, size_t ws_size,
                              hipStream_t stream)
{
    const float* x   = (const float*)d_in[0];
    const float* A   = (const float*)d_in[1];
    const float* Wqk = (const float*)d_in[2];
    const float* Wv  = (const float*)d_in[3];
    const float* g   = (const float*)d_in[4];
    const float* b   = (const float*)d_in[5];
    float* out = (float*)d_out;

    // Order matters: attn's dead wrap prefetch may run past kbuf into vT.
    float* partE = (float*)d_ws;                                   // 512 KB
    float* partF = partE + (size_t)NQT * HEADS * KSPLIT * QTILE;   // 512 KB
    unsigned short* qb   = (unsigned short*)(partF + (size_t)NQT * HEADS * KSPLIT * QTILE); // 1 MB
    unsigned short* kbuf = qb + (size_t)HEADS * NTOK * 16;         // 1 MB
    float* vT = (float*)(kbuf + (size_t)HEADS * NTOK * 16);        // 128 KB

    ln_qk_fused<<<dim3(NTOK / 16, 4), dim3(256), 0, stream>>>(
        x, Wqk, g, b, A, qb, kbuf, vT);
    attn_kernel<<<dim3(NQT, KSPLIT, HEADS), dim3(256), 0, stream>>>(
        qb, kbuf, vT, partE, partF);
    reduce_kernel<<<dim3(NTOK * HEADS / 256), dim3(256), 0, stream>>>(
        partE, partF, A, Wv, out);
}

// Round 6
// 33.279 us; speedup vs baseline: 2.7240x; 1.0420x over previous
//
#include <hip/hip_runtime.h>

#define HEADS 8
#define NTOK 4096
#define CH 128
#define KSPLIT 4
#define KCHUNK (NTOK / KSPLIT)   // 1024
#define LN_EPS 1e-5f

typedef short short8 __attribute__((ext_vector_type(8)));
typedef float f32x4 __attribute__((ext_vector_type(4)));
typedef float f32x2 __attribute__((ext_vector_type(2)));
typedef float f32x16 __attribute__((ext_vector_type(16)));

__device__ inline unsigned short f2bf(float f) {
    unsigned int u = __float_as_uint(f);
    u = (u + 0x7FFFu + ((u >> 16) & 1u)) >> 16;
    return (unsigned short)u;
}

__device__ inline float fast_exp2(float x) {
#if __has_builtin(__builtin_amdgcn_exp2f)
    return __builtin_amdgcn_exp2f(x);
#else
    float r; asm volatile("v_exp_f32 %0, %1" : "=v"(r) : "v"(x)); return r;
#endif
}

// packed f32 fma: lowers to v_pk_fma_f32 (VOP3P)
__device__ inline f32x2 fma2(f32x2 a, f32x2 b, f32x2 c) {
#if __has_builtin(__builtin_elementwise_fma)
    return __builtin_elementwise_fma(a, b, c);
#else
    f32x2 r; r.x = fmaf(a.x, b.x, c.x); r.y = fmaf(a.y, b.y, c.y); return r;
#endif
}

// softmax scale * log2(e), folded into q columns of W
#define SC (0.08838834764831845f * 1.4426950408889634f)

// ---------------------------------------------------------------------------
// Kernel A: LayerNorm + QK projection via MFMA, W-fragments built inline.
// Block = 16 rows x 4 waves; blockIdx.y = ct-group of 4; wave w owns
// ct = ctg*4 + w (ct<8 -> q head ct, ct>=8 -> k head ct-8).
// LDS tile is XOR-swizzled (c ^= (row&7)<<3 in shorts) to break the 16-way
// bank conflict on the ds_read_b128 A-fragment reads (row stride = 256 B).
// blockIdx.y==0 blocks additionally transpose A -> vT[h][n] for kernel B.
// ---------------------------------------------------------------------------
__global__ __launch_bounds__(256) void ln_qk_fused(
    const float* __restrict__ x, const float* __restrict__ Wqk,
    const float* __restrict__ g, const float* __restrict__ b,
    const float* __restrict__ A,
    unsigned short* __restrict__ qb, unsigned short* __restrict__ kbuf,
    float* __restrict__ vT)
{
    __shared__ __align__(16) unsigned short xn_s[16][CH];   // bf16, 4 KB
    const int tid = threadIdx.x;
    const int wave = tid >> 6, lane = tid & 63;
    const int row0 = blockIdx.x * 16;
    const int ct = blockIdx.y * 4 + wave;
    const int j = lane & 15, grp = lane >> 4;

    // Build B-fragments for this ct directly from W (L2-resident, 128 KB).
    // wf[ks]: lane holds W[ks*32 + grp*8 + jj][ct*16 + j], jj = 0..7.
    const float sc = (ct < 8) ? SC : 1.0f;
    short8 wf[4];
    #pragma unroll
    for (int ks = 0; ks < 4; ++ks) {
        unsigned int uu0, uu1, uu2, uu3;
        const float* wp = Wqk + (ks * 32 + grp * 8) * 256 + ct * 16 + j;
        uu0 = f2bf(wp[0 * 256] * sc) | ((unsigned)f2bf(wp[1 * 256] * sc) << 16);
        uu1 = f2bf(wp[2 * 256] * sc) | ((unsigned)f2bf(wp[3 * 256] * sc) << 16);
        uu2 = f2bf(wp[4 * 256] * sc) | ((unsigned)f2bf(wp[5 * 256] * sc) << 16);
        uu3 = f2bf(wp[6 * 256] * sc) | ((unsigned)f2bf(wp[7 * 256] * sc) << 16);
        uint4 packed = {uu0, uu1, uu2, uu3};
        wf[ks] = *(short8*)&packed;
    }

    // A transpose side-task (one ct-group is enough): vT[h][n] = A[n][h]
    if (blockIdx.y == 0 && tid < 128) {
        const int hh = tid >> 4, r = tid & 15;
        vT[hh * NTOK + row0 + r] = A[(size_t)(row0 + r) * HEADS + hh];
    }

    // LayerNorm: each wave handles 4 rows, 2 elements/lane
    for (int rr = wave; rr < 16; rr += 4) {
        const int row = row0 + rr;
        float2 xv = *(const float2*)(x + row * CH + lane * 2);
        float s  = xv.x + xv.y;
        float sq = xv.x * xv.x + xv.y * xv.y;
        #pragma unroll
        for (int off = 32; off >= 1; off >>= 1) {
            s  += __shfl_xor(s, off);
            sq += __shfl_xor(sq, off);
        }
        float mu  = s * (1.0f / CH);
        float var = sq * (1.0f / CH) - mu * mu;
        float rs  = rsqrtf(var + LN_EPS);
        float2 gv = *(const float2*)(g + lane * 2);
        float2 bv = *(const float2*)(b + lane * 2);
        unsigned int lo = f2bf((xv.x - mu) * rs * gv.x + bv.x);
        unsigned int hi = f2bf((xv.y - mu) * rs * gv.y + bv.y);
        const int c = (lane * 2) ^ ((rr & 7) << 3);      // swizzled column
        *(unsigned int*)&xn_s[rr][c] = lo | (hi << 16);
    }
    __syncthreads();

    // A-fragments: lane holds xn[row = lane&15][ks*32 + grp*8 + jj] (deswizzled)
    short8 af[4];
    #pragma unroll
    for (int ks = 0; ks < 4; ++ks)
        af[ks] = *(const short8*)(&xn_s[j][(ks * 32 + grp * 8) ^ ((j & 7) << 3)]);

    f32x4 acc = {0.f, 0.f, 0.f, 0.f};
    #pragma unroll
    for (int ks = 0; ks < 4; ++ks)
        acc = __builtin_amdgcn_mfma_f32_16x16x32_bf16(af[ks], wf[ks], acc, 0, 0, 0);

    // C/D layout: row = grp*4 + r, col = j
    unsigned short* dst = (ct < 8)
        ? qb   + ((size_t)ct * NTOK + row0) * 16
        : kbuf + ((size_t)(ct - 8) * NTOK + row0) * 16;
    #pragma unroll
    for (int r = 0; r < 4; ++r)
        dst[(grp * 4 + r) * 16 + j] = f2bf(acc[r]);
}

// ---------------------------------------------------------------------------
// Kernel B: MFMA attention via 32x32x16 (K = hd = 16, exact), with the
// split-K reduction folded into the block (LDS, no atomics/fences — r4
// lesson: per-block device fences = cross-XCD L2 invalidate storm).
// Block = 512 threads = 8 waves = 2 query-tiles x 4 key-splits:
// wave (qw = wave&1, ksp = wave>>1) computes queries qt*64 + qw*32 .. +32
// over keys ksp*1024 .. +1024. Inner loop identical to the proven r5 loop:
// one MFMA per 32 keys x 32 queries, K as A-operand, Q as B-operand,
// C/D map reg r -> key (r&3)+8*(r>>2)+4*(lane>>5), col -> query lane&31;
// 16 independent exps per MFMA; E/F as packed f32x2; one shfl_xor(32).
// Epilogue: per-wave (e,f) -> LDS, __syncthreads, threads 0..63 sum the
// 4 splits in s=0..3 order (bitwise-identical to the old reduce kernel)
// and write out = A + wv*F/E directly. Grid (64,8) = 2 blocks/CU =
// 4 waves/SIMD — same occupancy as r5.
// ---------------------------------------------------------------------------
__global__ __launch_bounds__(512, 4) void attn_kernel(
    const unsigned short* __restrict__ qb, const unsigned short* __restrict__ kbuf,
    const float* __restrict__ vT, const float* __restrict__ A,
    const float* __restrict__ Wv, float* __restrict__ out)
{
    const int tid = threadIdx.x;
    const int wave = tid >> 6, lane = tid & 63;
    const int qt = blockIdx.x, h = blockIdx.y;
    const int qw = wave & 1, ksp = wave >> 1;
    const int q0 = qt * 64 + qw * 32;
    const int m0 = ksp * KCHUNK;
    const int c  = lane & 31;      // row (key) / col (query) within tile
    const int hi = lane >> 5;      // k-dim half (0: k=0..7, 1: k=8..15)

    // Q as B-operand: lane holds Q[q0 + c][hi*8 + jj]
    short8 qf = *(const short8*)(qb + ((size_t)(h * NTOK + q0 + c) * 16 + hi * 8));

    // K as A-operand: lane holds K[m + c][hi*8 + jj]
    const unsigned short* kl = kbuf + ((size_t)(h * NTOK + m0 + c) * 16 + hi * 8);
    // v for reg-group g: keys m + 8g + 4*hi + {0..3}
    const float* vl = vT + h * NTOK + m0 + hi * 4;

    f32x2 E2 = {0.f, 0.f}, F2 = {0.f, 0.f};
    short8 kf = *(const short8*)kl;

    for (int mi = 0; mi < KCHUNK; mi += 32) {
        const int nx = (mi + 32 < KCHUNK) ? mi + 32 : 0;   // wrap: dead prefetch
        short8 kn = *(const short8*)(kl + (size_t)nx * 16);

        f32x4 v0 = *(const f32x4*)(vl + mi);
        f32x4 v1 = *(const f32x4*)(vl + mi + 8);
        f32x4 v2 = *(const f32x4*)(vl + mi + 16);
        f32x4 v3 = *(const f32x4*)(vl + mi + 24);

        f32x16 z = {0.f};
        f32x16 s = __builtin_amdgcn_mfma_f32_32x32x16_bf16(kf, qf, z, 0, 0, 0);

        #pragma unroll
        for (int gg = 0; gg < 4; ++gg) {
            f32x4 vg = (gg == 0) ? v0 : (gg == 1) ? v1 : (gg == 2) ? v2 : v3;
            f32x2 pa, pb;
            pa.x = fast_exp2(s[gg * 4 + 0]);
            pa.y = fast_exp2(s[gg * 4 + 1]);
            pb.x = fast_exp2(s[gg * 4 + 2]);
            pb.y = fast_exp2(s[gg * 4 + 3]);
            E2 += pa;
            E2 += pb;
            F2 = fma2(pa, vg.xy, F2);
            F2 = fma2(pb, vg.zw, F2);
        }
        kf = kn;
    }

    float e = E2.x + E2.y;
    float f = F2.x + F2.y;
    e += __shfl_xor(e, 32);
    f += __shfl_xor(f, 32);

    // in-block split-K reduce: LDS stage (conflict-free: 32 consecutive
    // floats per wave-half), then threads 0..63 finish 64 queries.
    __shared__ float eb[2][KSPLIT][32];
    __shared__ float fb[2][KSPLIT][32];
    if (lane < 32) {
        eb[qw][ksp][c] = e;
        fb[qw][ksp][c] = f;
    }
    __syncthreads();

    if (tid < 64) {
        const int qw2 = tid >> 5, c2 = tid & 31;
        float E = eb[qw2][0][c2], F = fb[qw2][0][c2];
        #pragma unroll
        for (int s = 1; s < KSPLIT; ++s) {
            E += eb[qw2][s][c2];
            F += fb[qw2][s][c2];
        }
        const int q = qt * 64 + qw2 * 32 + c2;
        out[q * HEADS + h] = A[q * HEADS + h] + Wv[0] * F / E;
    }
}

// ---------------------------------------------------------------------------
extern "C" void kernel_launch(void* const* d_in, const int* in_sizes, int n_in,
                              void* d_out, int out_size, void* d_ws, size_t ws_size,
                              hipStream_t stream)
{
    const float* x   = (const float*)d_in[0];
    const float* A   = (const float*)d_in[1];
    const float* Wqk = (const float*)d_in[2];
    const float* Wv  = (const float*)d_in[3];
    const float* g   = (const float*)d_in[4];
    const float* b   = (const float*)d_in[5];
    float* out = (float*)d_out;

    unsigned short* qb   = (unsigned short*)d_ws;                  // 1 MB
    unsigned short* kbuf = qb + (size_t)HEADS * NTOK * 16;         // 1 MB
    float* vT = (float*)(kbuf + (size_t)HEADS * NTOK * 16);        // 128 KB

    ln_qk_fused<<<dim3(NTOK / 16, 4), dim3(256), 0, stream>>>(
        x, Wqk, g, b, A, qb, kbuf, vT);
    attn_kernel<<<dim3(NTOK / 64, HEADS), dim3(512), 0, stream>>>(
        qb, kbuf, vT, A, Wv, out);
}

// Round 7
// 33.010 us; speedup vs baseline: 2.7462x; 1.0082x over previous
//
#include <hip/hip_runtime.h>

#define HEADS 8
#define NTOK 4096
#define CH 128
#define KSPLIT 8
#define KCHUNK (NTOK / KSPLIT)   // 512
#define LN_EPS 1e-5f

typedef short short8 __attribute__((ext_vector_type(8)));
typedef float f32x4 __attribute__((ext_vector_type(4)));
typedef float f32x2 __attribute__((ext_vector_type(2)));
typedef float f32x16 __attribute__((ext_vector_type(16)));

__device__ inline unsigned short f2bf(float f) {
    unsigned int u = __float_as_uint(f);
    u = (u + 0x7FFFu + ((u >> 16) & 1u)) >> 16;
    return (unsigned short)u;
}

__device__ inline float fast_exp2(float x) {
#if __has_builtin(__builtin_amdgcn_exp2f)
    return __builtin_amdgcn_exp2f(x);
#else
    float r; asm volatile("v_exp_f32 %0, %1" : "=v"(r) : "v"(x)); return r;
#endif
}

// packed f32 fma: lowers to v_pk_fma_f32 (VOP3P)
__device__ inline f32x2 fma2(f32x2 a, f32x2 b, f32x2 c) {
#if __has_builtin(__builtin_elementwise_fma)
    return __builtin_elementwise_fma(a, b, c);
#else
    f32x2 r; r.x = fmaf(a.x, b.x, c.x); r.y = fmaf(a.y, b.y, c.y); return r;
#endif
}

// softmax scale * log2(e), folded into q columns of W
#define SC (0.08838834764831845f * 1.4426950408889634f)

// ---------------------------------------------------------------------------
// Kernel A: LayerNorm + QK projection via MFMA, W-fragments built inline.
// Block = 16 rows x 4 waves; blockIdx.y = ct-group of 4; wave w owns
// ct = ctg*4 + w (ct<8 -> q head ct, ct>=8 -> k head ct-8).
// LDS tile is XOR-swizzled (c ^= (row&7)<<3 in shorts) to break the 16-way
// bank conflict on the ds_read_b128 A-fragment reads (row stride = 256 B).
// blockIdx.y==0 blocks additionally transpose A -> vT[h][n] for kernel B.
// ---------------------------------------------------------------------------
__global__ __launch_bounds__(256) void ln_qk_fused(
    const float* __restrict__ x, const float* __restrict__ Wqk,
    const float* __restrict__ g, const float* __restrict__ b,
    const float* __restrict__ A,
    unsigned short* __restrict__ qb, unsigned short* __restrict__ kbuf,
    float* __restrict__ vT)
{
    __shared__ __align__(16) unsigned short xn_s[16][CH];   // bf16, 4 KB
    const int tid = threadIdx.x;
    const int wave = tid >> 6, lane = tid & 63;
    const int row0 = blockIdx.x * 16;
    const int ct = blockIdx.y * 4 + wave;
    const int j = lane & 15, grp = lane >> 4;

    // Build B-fragments for this ct directly from W (L2-resident, 128 KB).
    // wf[ks]: lane holds W[ks*32 + grp*8 + jj][ct*16 + j], jj = 0..7.
    const float sc = (ct < 8) ? SC : 1.0f;
    short8 wf[4];
    #pragma unroll
    for (int ks = 0; ks < 4; ++ks) {
        unsigned int uu0, uu1, uu2, uu3;
        const float* wp = Wqk + (ks * 32 + grp * 8) * 256 + ct * 16 + j;
        uu0 = f2bf(wp[0 * 256] * sc) | ((unsigned)f2bf(wp[1 * 256] * sc) << 16);
        uu1 = f2bf(wp[2 * 256] * sc) | ((unsigned)f2bf(wp[3 * 256] * sc) << 16);
        uu2 = f2bf(wp[4 * 256] * sc) | ((unsigned)f2bf(wp[5 * 256] * sc) << 16);
        uu3 = f2bf(wp[6 * 256] * sc) | ((unsigned)f2bf(wp[7 * 256] * sc) << 16);
        uint4 packed = {uu0, uu1, uu2, uu3};
        wf[ks] = *(short8*)&packed;
    }

    // A transpose side-task (one ct-group is enough): vT[h][n] = A[n][h]
    if (blockIdx.y == 0 && tid < 128) {
        const int hh = tid >> 4, r = tid & 15;
        vT[hh * NTOK + row0 + r] = A[(size_t)(row0 + r) * HEADS + hh];
    }

    // LayerNorm: each wave handles 4 rows, 2 elements/lane
    for (int rr = wave; rr < 16; rr += 4) {
        const int row = row0 + rr;
        float2 xv = *(const float2*)(x + row * CH + lane * 2);
        float s  = xv.x + xv.y;
        float sq = xv.x * xv.x + xv.y * xv.y;
        #pragma unroll
        for (int off = 32; off >= 1; off >>= 1) {
            s  += __shfl_xor(s, off);
            sq += __shfl_xor(sq, off);
        }
        float mu  = s * (1.0f / CH);
        float var = sq * (1.0f / CH) - mu * mu;
        float rs  = rsqrtf(var + LN_EPS);
        float2 gv = *(const float2*)(g + lane * 2);
        float2 bv = *(const float2*)(b + lane * 2);
        unsigned int lo = f2bf((xv.x - mu) * rs * gv.x + bv.x);
        unsigned int hi = f2bf((xv.y - mu) * rs * gv.y + bv.y);
        const int c = (lane * 2) ^ ((rr & 7) << 3);      // swizzled column
        *(unsigned int*)&xn_s[rr][c] = lo | (hi << 16);
    }
    __syncthreads();

    // A-fragments: lane holds xn[row = lane&15][ks*32 + grp*8 + jj] (deswizzled)
    short8 af[4];
    #pragma unroll
    for (int ks = 0; ks < 4; ++ks)
        af[ks] = *(const short8*)(&xn_s[j][(ks * 32 + grp * 8) ^ ((j & 7) << 3)]);

    f32x4 acc = {0.f, 0.f, 0.f, 0.f};
    #pragma unroll
    for (int ks = 0; ks < 4; ++ks)
        acc = __builtin_amdgcn_mfma_f32_16x16x32_bf16(af[ks], wf[ks], acc, 0, 0, 0);

    // C/D layout: row = grp*4 + r, col = j
    unsigned short* dst = (ct < 8)
        ? qb   + ((size_t)ct * NTOK + row0) * 16
        : kbuf + ((size_t)(ct - 8) * NTOK + row0) * 16;
    #pragma unroll
    for (int r = 0; r < 4; ++r)
        dst[(grp * 4 + r) * 16 + j] = f2bf(acc[r]);
}

// ---------------------------------------------------------------------------
// Kernel B: MFMA attention via 32x32x16 (K = hd = 16, exact), in-block
// split-K (LDS reduce, no atomics/fences — r4 lesson).
// Block = 512 threads = 8 waves = ONE 32-query tile x 8 key-splits:
// wave ksp computes queries qt*32..+32 over keys ksp*512..+512 (16 iters).
// Inner loop byte-identical to the proven r5/r6 loop: one MFMA per
// 32 keys x 32 queries, K as A-operand, Q as B-operand, C/D map
// reg r -> key (r&3)+8*(r>>2)+4*(lane>>5), col -> query lane&31;
// 16 independent exps per MFMA; E/F packed f32x2; one shfl_xor(32).
// Occupancy: grid (128,8) = 1024 blocks = 4 blocks/CU = 8 waves/SIMD
// (VGPR 56 <= 64; __launch_bounds__(512,8) pins the register budget) —
// doubles TLP vs r6 to cover the in-iter v-load / K-stream latency.
// ---------------------------------------------------------------------------
__global__ __launch_bounds__(512, 8) void attn_kernel(
    const unsigned short* __restrict__ qb, const unsigned short* __restrict__ kbuf,
    const float* __restrict__ vT, const float* __restrict__ A,
    const float* __restrict__ Wv, float* __restrict__ out)
{
    const int tid = threadIdx.x;
    const int ksp = tid >> 6, lane = tid & 63;
    const int qt = blockIdx.x, h = blockIdx.y;
    const int q0 = qt * 32;
    const int m0 = ksp * KCHUNK;
    const int c  = lane & 31;      // row (key) / col (query) within tile
    const int hi = lane >> 5;      // k-dim half (0: k=0..7, 1: k=8..15)

    // Q as B-operand: lane holds Q[q0 + c][hi*8 + jj]
    short8 qf = *(const short8*)(qb + ((size_t)(h * NTOK + q0 + c) * 16 + hi * 8));

    // K as A-operand: lane holds K[m + c][hi*8 + jj]
    const unsigned short* kl = kbuf + ((size_t)(h * NTOK + m0 + c) * 16 + hi * 8);
    // v for reg-group g: keys m + 8g + 4*hi + {0..3}
    const float* vl = vT + h * NTOK + m0 + hi * 4;

    f32x2 E2 = {0.f, 0.f}, F2 = {0.f, 0.f};
    short8 kf = *(const short8*)kl;

    for (int mi = 0; mi < KCHUNK; mi += 32) {
        const int nx = (mi + 32 < KCHUNK) ? mi + 32 : 0;   // wrap: dead prefetch
        short8 kn = *(const short8*)(kl + (size_t)nx * 16);

        f32x4 v0 = *(const f32x4*)(vl + mi);
        f32x4 v1 = *(const f32x4*)(vl + mi + 8);
        f32x4 v2 = *(const f32x4*)(vl + mi + 16);
        f32x4 v3 = *(const f32x4*)(vl + mi + 24);

        f32x16 z = {0.f};
        f32x16 s = __builtin_amdgcn_mfma_f32_32x32x16_bf16(kf, qf, z, 0, 0, 0);

        #pragma unroll
        for (int gg = 0; gg < 4; ++gg) {
            f32x4 vg = (gg == 0) ? v0 : (gg == 1) ? v1 : (gg == 2) ? v2 : v3;
            f32x2 pa, pb;
            pa.x = fast_exp2(s[gg * 4 + 0]);
            pa.y = fast_exp2(s[gg * 4 + 1]);
            pb.x = fast_exp2(s[gg * 4 + 2]);
            pb.y = fast_exp2(s[gg * 4 + 3]);
            E2 += pa;
            E2 += pb;
            F2 = fma2(pa, vg.xy, F2);
            F2 = fma2(pb, vg.zw, F2);
        }
        kf = kn;
    }

    float e = E2.x + E2.y;
    float f = F2.x + F2.y;
    e += __shfl_xor(e, 32);
    f += __shfl_xor(f, 32);

    // in-block split-K reduce: LDS stage (conflict-free: 32 consecutive
    // floats per wave), then threads 0..31 finish the 32 queries.
    __shared__ float eb[KSPLIT][32];
    __shared__ float fb[KSPLIT][32];
    if (lane < 32) {
        eb[ksp][c] = e;
        fb[ksp][c] = f;
    }
    __syncthreads();

    if (tid < 32) {
        float E = eb[0][tid], F = fb[0][tid];
        #pragma unroll
        for (int s = 1; s < KSPLIT; ++s) {
            E += eb[s][tid];
            F += fb[s][tid];
        }
        const int q = qt * 32 + tid;
        out[q * HEADS + h] = A[q * HEADS + h] + Wv[0] * F / E;
    }
}

// ---------------------------------------------------------------------------
extern "C" void kernel_launch(void* const* d_in, const int* in_sizes, int n_in,
                              void* d_out, int out_size, void* d_ws, size_t ws_size,
                              hipStream_t stream)
{
    const float* x   = (const float*)d_in[0];
    const float* A   = (const float*)d_in[1];
    const float* Wqk = (const float*)d_in[2];
    const float* Wv  = (const float*)d_in[3];
    const float* g   = (const float*)d_in[4];
    const float* b   = (const float*)d_in[5];
    float* out = (float*)d_out;

    unsigned short* qb   = (unsigned short*)d_ws;                  // 1 MB
    unsigned short* kbuf = qb + (size_t)HEADS * NTOK * 16;         // 1 MB
    float* vT = (float*)(kbuf + (size_t)HEADS * NTOK * 16);        // 128 KB

    ln_qk_fused<<<dim3(NTOK / 16, 4), dim3(256), 0, stream>>>(
        x, Wqk, g, b, A, qb, kbuf, vT);
    attn_kernel<<<dim3(NTOK / 32, HEADS), dim3(512), 0, stream>>>(
        qb, kbuf, vT, A, Wv, out);
}